// Round 4
// baseline (361.972 us; speedup 1.0000x reference)
//
#include <hip/hip_runtime.h>

// BackEdgeConv2d: out = x * !(5 <= boxsum7x7(x >= 128/255, reflect-pad) <= 19)
// x: [16, 3, 1024, 1024] fp32.
//
// R6: R5 measured 137us, VGPR=84, FETCH 269->139MB yet time ~unchanged ->
// latency-bound confirmed, and VGPR=84 proves the compiler SANK the R5
// prefetch ring to point-of-use (84 = ~3-row minimum forced by the output
// pass-through, not the 5-row ring). Little's law at ~4KB/wave in flight,
// ~1500cy congested latency, 12 waves/CU gives exactly the observed
// ~2.5-3.4 TB/s. Fix: explicit prefetch distance P=2 (ring D=6) with
// __builtin_amdgcn_sched_barrier(0) after each step's load-issue block so
// the scheduler cannot sink loads across the step boundary. Keeps 8-12
// loads/wave outstanding -> ~80 B/cyc/CU MLP headroom vs ~17 needed.
//
// Ring slot algebra (D=6, P=2): row r issued at step r-2 into slot r%6;
// threshold-consumed at step r; output-consumed at step r+3; overwritten
// by row r+6's issue at step r+4.  All disjoint.
//
// Layout per wave (verified): lane i owns one float4 per quarter-row
// (cols 256q+4i..+3) -> every load/store is a wave-contiguous 1KB
// transaction. Horizontal 7-sums via shfl neighbors + popc; vertical 7-row
// sliding sum in byte-packed u32s; nibble-packed h-sum history.
// No LDS, no barriers.

constexpr int H = 1024;
constexpr int W = 1024;
constexpr int BH = 16;           // rows per band (per wave)
constexpr int NBANDS = H / BH;   // 64
constexpr int STEPS = BH + 6;    // 22 stencil rows per band
constexpr int P = 2;             // prefetch distance (rows ahead)
constexpr int D = P + 4;         // 6 ring slots: covers s-3 .. s+P

typedef float vfloat4 __attribute__((ext_vector_type(4)));

__device__ __forceinline__ void nt_store4(float* p, float4 v) {
    vfloat4 t;
    t.x = v.x; t.y = v.y; t.z = v.z; t.w = v.w;
    __builtin_nontemporal_store(t, (vfloat4*)p);
}

__device__ __forceinline__ int reflect_row(int g) {
    g = (g < 0) ? -g : g;
    return (g >= H) ? (2 * H - 2 - g) : g;
}

__device__ __forceinline__ unsigned expand4(unsigned n) {
    // 4 nibbles (in a u16) -> 4 bytes
    unsigned t = (n | (n << 8)) & 0x00FF00FFu;
    return (t | (t << 4)) & 0x0F0F0F0Fu;
}
__device__ __forceinline__ unsigned compress4(unsigned b) {
    // 4 bytes (each <= 15) -> 4 nibbles (u16)
    unsigned t = (b | (b >> 4)) & 0x00FF00FFu;
    return (t | (t >> 8)) & 0x0000FFFFu;
}

__global__ __launch_bounds__(256, 3)
void backedge_kernel(const float* __restrict__ x, float* __restrict__ out) {
    const int lane = threadIdx.x & 63;
    const int wv   = threadIdx.x >> 6;            // 0..3, independent waves
    const int band = blockIdx.x * 4 + wv;         // 0..63
    const int n    = blockIdx.y;                  // 0..47 (B*C)
    const int r0   = band * BH;
    const float* __restrict__ xi = x   + (size_t)n * (size_t)(H * W);
    float*       __restrict__ oi = out + (size_t)n * (size_t)(H * W);
    const int off = 4 * lane;                     // float offset inside a quarter
    const float THR = 128.0f / 255.0f;

    float4 ring[D][4];                            // raw rows, 96 VGPRs
    unsigned int hn[7][2];                        // nibble-packed h-sums, 14 VGPRs
#pragma unroll
    for (int i = 0; i < 7; ++i) { hn[i][0] = 0u; hn[i][1] = 0u; }
    unsigned int vs[4] = {0u, 0u, 0u, 0u};        // byte-packed vertical sums

    // prologue: issue loads for steps 0..P-1 (rows reflect(r0-3..r0-3+P-1))
#pragma unroll
    for (int j = 0; j < P; ++j) {
        const float* rp = xi + (size_t)reflect_row(r0 - 3 + j) * W;
#pragma unroll
        for (int q = 0; q < 4; ++q)
            ring[j][q] = *(const float4*)(rp + q * 256 + off);
    }

#pragma unroll
    for (int s = 0; s < STEPS; ++s) {
        // ---- issue loads for row s+P into slot (s+P)%D ----
        if (s + P < STEPS) {
            const float* rp = xi + (size_t)reflect_row(r0 - 3 + s + P) * W;
#pragma unroll
            for (int q = 0; q < 4; ++q)
                ring[(s + P) % D][q] = *(const float4*)(rp + q * 256 + off);
        }
        // pin the issue point: scheduler may not sink these loads past here
        __builtin_amdgcn_sched_barrier(0);

        // ---- 16 threshold bits from row s: bit 4q+j <-> col 256q+4*lane+j ----
        unsigned int m = 0;
#pragma unroll
        for (int q = 0; q < 4; ++q) {
            const float4 aq = ring[s % D][q];
            m |= ((unsigned)(aq.x >= THR)) << (4 * q + 0);
            m |= ((unsigned)(aq.y >= THR)) << (4 * q + 1);
            m |= ((unsigned)(aq.z >= THR)) << (4 * q + 2);
            m |= ((unsigned)(aq.w >= THR)) << (4 * q + 3);
        }

        const unsigned int up = __shfl_up(m, 1);    // lane i-1's mask
        const unsigned int dn = __shfl_down(m, 1);  // lane i+1's mask
        const unsigned int hi = __shfl(m, 63);      // lane 63 broadcast
        const unsigned int lo = __shfl(m, 0);       // lane 0 broadcast
        // left-neighbor source: quarter q of SL supplies cols 256q+4i-4..-1
        const unsigned int SL = (lane == 0) ? (hi << 4) : up;
        // right-neighbor source: quarter q of SR supplies cols 256q+4i+4..+7
        const unsigned int SR = (lane == 63) ? (lo >> 4) : dn;

        unsigned int hp[4];
#pragma unroll
        for (int q = 0; q < 4; ++q) {
            // w bit k <-> col (256q + 4*lane) + k - 3   (10 bits used)
            unsigned int w = ((SL >> (4 * q + 1)) & 7u)
                           | (((m >> (4 * q)) & 0xFu) << 3)
                           | (((SR >> (4 * q)) & 7u) << 7);
            if (q == 0 && lane == 0) {
                // cols -3,-2,-1 reflect -> cols 3,2,1 (own bits 3,2,1)
                w |= ((m >> 3) & 1u) | (((m >> 2) & 1u) << 1)
                   | (((m >> 1) & 1u) << 2);
            }
            if (q == 3 && lane == 63) {
                // cols 1024,1025,1026 reflect -> 1022,1021,1020 (bits 14,13,12)
                w |= (((m >> 14) & 1u) << 7) | (((m >> 13) & 1u) << 8)
                   | (((m >> 12) & 1u) << 9);
            }
            const unsigned int h0 = __popc((w >> 0) & 0x7Fu);
            const unsigned int h1 = __popc((w >> 1) & 0x7Fu);
            const unsigned int h2 = __popc((w >> 2) & 0x7Fu);
            const unsigned int h3 = __popc((w >> 3) & 0x7Fu);
            hp[q] = h0 | (h1 << 8) | (h2 << 16) | (h3 << 24);
        }

        // ---- vertical sliding sum (byte digits <= 49, never carry) ----
        vs[0] += hp[0] - expand4(hn[0][0] & 0xFFFFu);
        vs[1] += hp[1] - expand4(hn[0][0] >> 16);
        vs[2] += hp[2] - expand4(hn[0][1] & 0xFFFFu);
        vs[3] += hp[3] - expand4(hn[0][1] >> 16);
#pragma unroll
        for (int i = 0; i < 6; ++i) {
            hn[i][0] = hn[i + 1][0];
            hn[i][1] = hn[i + 1][1];
        }
        hn[6][0] = compress4(hp[0]) | (compress4(hp[1]) << 16);
        hn[6][1] = compress4(hp[2]) | (compress4(hp[3]) << 16);

        // ---- output row r0+s-6; its raw x lives in ring slot (s-3)%D ----
        if (s >= 6) {
            const int orow = r0 + s - 6;
            float* op = oi + (size_t)orow * W;
#pragma unroll
            for (int q = 0; q < 4; ++q) {
                const float4 b = ring[(s - 3) % D][q];
                const unsigned int v = vs[q];
                float4 o;
                // zeroed iff 5 <= csum <= 19  <=>  (csum-5) <= 14 unsigned
                o.x = ((((v      ) & 0xFFu) - 5u) <= 14u) ? 0.0f : b.x;
                o.y = ((((v >>  8) & 0xFFu) - 5u) <= 14u) ? 0.0f : b.y;
                o.z = ((((v >> 16) & 0xFFu) - 5u) <= 14u) ? 0.0f : b.z;
                o.w = ((((v >> 24)        ) - 5u) <= 14u) ? 0.0f : b.w;
                nt_store4(op + q * 256 + off, o);
            }
        }
    }
}

extern "C" void kernel_launch(void* const* d_in, const int* in_sizes, int n_in,
                              void* d_out, int out_size, void* d_ws, size_t ws_size,
                              hipStream_t stream) {
    const float* x = (const float*)d_in[0];
    float* out = (float*)d_out;
    (void)in_sizes; (void)n_in; (void)d_ws; (void)ws_size; (void)out_size;
    dim3 grid(NBANDS / 4, 16 * 3);   // 16 x 48 = 768 blocks of 256 (4 waves/block)
    backedge_kernel<<<grid, dim3(256), 0, stream>>>(x, out);
}

// Round 7
// 352.056 us; speedup vs baseline: 1.0282x; 1.0282x over previous
//
#include <hip/hip_runtime.h>

// BackEdgeConv2d: out = x * !(5 <= boxsum7x7(x >= 128/255, reflect-pad) <= 19)
// x: [16, 3, 1024, 1024] fp32.
//
// R9: rolled-loop version of the verified R5 dataflow (absmax=0 at 137us).
// R7/R8 (hand-vmcnt inline asm) both NaN'd: with "=v" virtual outputs the
// register allocator may insert live-range-split copies of in-flight load
// dests (or reuse store-source regs) between asm issue and the hand wait --
// unfixable at source level. Abandoned.
//
// Why code size: R2/R5/R6 all ~140us (330k cy = ~5000 cy/step-slot) while
// VALUBusy 15%, BW 32-42% of peak, occupancy as designed -- no memory or
// compute model closes 5000 cy/step. All three were fully-unrolled 14-22
// step bodies (~20-30KB of code) with 12 waves/CU at different offsets
// streaming through a 32KB L1I: a permanent I-fetch miss stream at L2
// latency is the only mechanism with the right magnitude, and it predicts
// exactly the observed invariance to memory-side changes.
// Fix: peel steps 0-1, then  #pragma unroll 1  over 4 iterations x 5
// templated instances (s = 2+5j+k, so s mod 5 = (2+k)%5 is loop-invariant
// -> all ring indices compile-time, no scratch). ~7 step instances ~= 8KB.
// Edge conditions (store s>=6, load s+1<22) are uniform scalar guards.
//
// Dataflow per wave (verified R2-R6): lane i owns one float4 per
// quarter-row (cols 256q+4i..+3); 5-deep raw-row ring (slot r%5: written
// @r-1, threshold-read @r, output-read @r+3, redefined @r+4); horizontal
// 7-sums via shfl + popc; vertical 7-row sliding sum byte-packed;
// nibble-packed h-sum history. Plain loads/stores (nt amplified WRITE in
// R5/R6; plain measured ~197MB in R2). No LDS, no barriers.

constexpr int H = 1024;
constexpr int W = 1024;
constexpr int BH = 16;           // rows per band (per wave)
constexpr int NBANDS = H / BH;   // 64
constexpr int STEPS = BH + 6;    // 22

__device__ __forceinline__ int reflect_row(int g) {
    g = (g < 0) ? -g : g;
    return (g >= H) ? (2 * H - 2 - g) : g;
}
__device__ __forceinline__ unsigned expand4(unsigned n) {
    unsigned t = (n | (n << 8)) & 0x00FF00FFu;
    return (t | (t << 4)) & 0x0F0F0F0Fu;
}
__device__ __forceinline__ unsigned compress4(unsigned b) {
    unsigned t = (b | (b >> 4)) & 0x00FF00FFu;
    return (t | (t >> 8)) & 0x0000FFFFu;
}

template <int CUR>
__device__ __forceinline__ void do_step(int s, float4 (&ring)[5][4],
                                        unsigned (&hn)[7][2], unsigned (&vs)[4],
                                        const float* xi, float* oi,
                                        int r0, int off, int lane) {
    constexpr int NXT = (CUR + 1) % 5;   // slot for row s+1
    constexpr int PQ  = (CUR + 2) % 5;   // slot holding row s-3 (output x)

    // ---- load row s+1 into slot NXT (uniform scalar guard) ----
    if (s + 1 < STEPS) {
        const float* rp = xi + (size_t)reflect_row(r0 - 3 + s + 1) * W;
#pragma unroll
        for (int q = 0; q < 4; ++q)
            ring[NXT][q] = *(const float4*)(rp + q * 256 + off);
    }

    // ---- 16 threshold bits from row s: bit 4q+j <-> col 256q+4*lane+j ----
    const float THR = 128.0f / 255.0f;
    unsigned m = 0;
#pragma unroll
    for (int q = 0; q < 4; ++q) {
        const float4 aq = ring[CUR][q];
        m |= ((unsigned)(aq.x >= THR)) << (4 * q + 0);
        m |= ((unsigned)(aq.y >= THR)) << (4 * q + 1);
        m |= ((unsigned)(aq.z >= THR)) << (4 * q + 2);
        m |= ((unsigned)(aq.w >= THR)) << (4 * q + 3);
    }

    const unsigned up = __shfl_up(m, 1);
    const unsigned dn = __shfl_down(m, 1);
    const unsigned hi = __shfl(m, 63);
    const unsigned lo = __shfl(m, 0);
    const unsigned SL = (lane == 0) ? (hi << 4) : up;
    const unsigned SR = (lane == 63) ? (lo >> 4) : dn;

    unsigned hp[4];
#pragma unroll
    for (int q = 0; q < 4; ++q) {
        unsigned w = ((SL >> (4 * q + 1)) & 7u)
                   | (((m >> (4 * q)) & 0xFu) << 3)
                   | (((SR >> (4 * q)) & 7u) << 7);
        if (q == 0 && lane == 0) {
            // cols -3,-2,-1 reflect -> cols 3,2,1 (own bits 3,2,1)
            w |= ((m >> 3) & 1u) | (((m >> 2) & 1u) << 1) | (((m >> 1) & 1u) << 2);
        }
        if (q == 3 && lane == 63) {
            // cols 1024,1025,1026 reflect -> 1022,1021,1020 (bits 14,13,12)
            w |= (((m >> 14) & 1u) << 7) | (((m >> 13) & 1u) << 8) | (((m >> 12) & 1u) << 9);
        }
        const unsigned h0 = __popc((w >> 0) & 0x7Fu);
        const unsigned h1 = __popc((w >> 1) & 0x7Fu);
        const unsigned h2 = __popc((w >> 2) & 0x7Fu);
        const unsigned h3 = __popc((w >> 3) & 0x7Fu);
        hp[q] = h0 | (h1 << 8) | (h2 << 16) | (h3 << 24);
    }

    // ---- vertical sliding sum (byte digits <= 49, never carry) ----
    vs[0] += hp[0] - expand4(hn[0][0] & 0xFFFFu);
    vs[1] += hp[1] - expand4(hn[0][0] >> 16);
    vs[2] += hp[2] - expand4(hn[0][1] & 0xFFFFu);
    vs[3] += hp[3] - expand4(hn[0][1] >> 16);
#pragma unroll
    for (int i = 0; i < 6; ++i) {
        hn[i][0] = hn[i + 1][0];
        hn[i][1] = hn[i + 1][1];
    }
    hn[6][0] = compress4(hp[0]) | (compress4(hp[1]) << 16);
    hn[6][1] = compress4(hp[2]) | (compress4(hp[3]) << 16);

    // ---- output row r0+s-6; raw x from ring slot PQ (uniform guard) ----
    if (s >= 6) {
        float* op = oi + (size_t)(r0 + s - 6) * W;
#pragma unroll
        for (int q = 0; q < 4; ++q) {
            const float4 b = ring[PQ][q];
            const unsigned v = vs[q];
            float4 o;
            // zeroed iff 5 <= csum <= 19  <=>  (csum-5) <= 14 unsigned
            o.x = ((((v      ) & 0xFFu) - 5u) <= 14u) ? 0.0f : b.x;
            o.y = ((((v >>  8) & 0xFFu) - 5u) <= 14u) ? 0.0f : b.y;
            o.z = ((((v >> 16) & 0xFFu) - 5u) <= 14u) ? 0.0f : b.z;
            o.w = ((((v >> 24)        ) - 5u) <= 14u) ? 0.0f : b.w;
            *(float4*)(op + q * 256 + off) = o;
        }
    }
}

__global__ __launch_bounds__(256, 3)
void backedge_kernel(const float* __restrict__ x, float* __restrict__ out) {
    const int lane = threadIdx.x & 63;
    const int wv   = threadIdx.x >> 6;            // 0..3, independent waves
    const int band = blockIdx.x * 4 + wv;         // 0..63
    const int n    = blockIdx.y;                  // 0..47 (B*C)
    const int r0   = band * BH;
    const float* xi = x   + (size_t)n * (size_t)(H * W);
    float*       oi = out + (size_t)n * (size_t)(H * W);
    const int off = 4 * lane;                     // float offset inside a quarter

    float4 ring[5][4];                            // raw rows, 80 VGPRs
    unsigned hn[7][2];                            // nibble-packed h-sums
#pragma unroll
    for (int i = 0; i < 7; ++i) { hn[i][0] = 0u; hn[i][1] = 0u; }
    unsigned vs[4] = {0u, 0u, 0u, 0u};            // byte-packed vertical sums

    // prologue: load row 0 (= reflect(r0-3)) into slot 0
    {
        const float* rp = xi + (size_t)reflect_row(r0 - 3) * W;
#pragma unroll
        for (int q = 0; q < 4; ++q)
            ring[0][q] = *(const float4*)(rp + q * 256 + off);
    }

    // peel steps 0,1 (no store; slots 0,1 current)
    do_step<0>(0, ring, hn, vs, xi, oi, r0, off, lane);
    do_step<1>(1, ring, hn, vs, xi, oi, r0, off, lane);

    // rolled: s = 2+5j+k, k=0..4 -> s%5 = (2+k)%5 loop-invariant
#pragma unroll 1
    for (int j = 0; j < 4; ++j) {
        const int s = 2 + 5 * j;
        do_step<2>(s    , ring, hn, vs, xi, oi, r0, off, lane);
        do_step<3>(s + 1, ring, hn, vs, xi, oi, r0, off, lane);
        do_step<4>(s + 2, ring, hn, vs, xi, oi, r0, off, lane);
        do_step<0>(s + 3, ring, hn, vs, xi, oi, r0, off, lane);
        do_step<1>(s + 4, ring, hn, vs, xi, oi, r0, off, lane);
    }
}

extern "C" void kernel_launch(void* const* d_in, const int* in_sizes, int n_in,
                              void* d_out, int out_size, void* d_ws, size_t ws_size,
                              hipStream_t stream) {
    const float* x = (const float*)d_in[0];
    float* out = (float*)d_out;
    (void)in_sizes; (void)n_in; (void)d_ws; (void)ws_size; (void)out_size;
    dim3 grid(NBANDS / 4, 16 * 3);   // 16 x 48 = 768 blocks of 256 (4 waves/block)
    backedge_kernel<<<grid, dim3(256), 0, stream>>>(x, out);
}